// Round 3
// baseline (5989.137 us; speedup 1.0000x reference)
//
#include <hip/hip_runtime.h>
#include <math.h>

#define DIN   192
#define HD    256
#define ROWS  64
#define THREADS 512
#define LSTR  256   // LDS row stride (elems); banking fixed by XOR swizzle

typedef __bf16 bf16_t;
typedef bf16_t bf16x8 __attribute__((ext_vector_type(8)));
typedef float  f32x4  __attribute__((ext_vector_type(4)));

static __device__ __forceinline__ f32x4 mfma16(bf16x8 a, bf16x8 b, f32x4 c) {
  return __builtin_amdgcn_mfma_f32_16x16x32_bf16(a, b, c, 0, 0, 0);
}
static __device__ __forceinline__ unsigned short f2bfu(float f) {
  bf16_t h = (bf16_t)f; unsigned short u; __builtin_memcpy(&u, &h, 2); return u;
}
static __device__ __forceinline__ float bfu2f(unsigned short u) {
  unsigned x = ((unsigned)u) << 16; float f; __builtin_memcpy(&f, &x, 4); return f;
}
static __device__ __forceinline__ unsigned pk2(float a, float b) {
  return (unsigned)f2bfu(a) | ((unsigned)f2bfu(b) << 16);
}
static __device__ __forceinline__ float sigm(float x) {
  return __builtin_amdgcn_rcpf(1.f + __expf(-x));
}
// XOR-swizzled LDS element index: spreads strided row access across banks.
static __device__ __forceinline__ int lidx(int row, int col) {
  return row * LSTR + (col ^ ((row & 7) << 3));
}

// bf16 weight region layout (elements) inside d_ws after the scores buffer
#define OFF_WSW1 0
#define OFF_WSS1 49152
#define OFF_WSG1 98304
#define OFF_WSC1 147456
#define OFF_WSW2 212992
#define OFF_WSS2 278528
#define OFF_WSG2 344064
#define OFF_WSC2 409600
#define OFF_WOUT 475136
#define W_TOTAL  476160

__global__ void iab_wconv_kernel(const float* __restrict__ a0, const float* __restrict__ a1,
                                 const float* __restrict__ a2, const float* __restrict__ a3,
                                 const float* __restrict__ a4, const float* __restrict__ a5,
                                 const float* __restrict__ a6, const float* __restrict__ a7,
                                 const float* __restrict__ a8, unsigned short* __restrict__ out)
{
  const int i = blockIdx.x * 256 + threadIdx.x;
  if (i >= W_TOTAL) return;
  const float* src; int off;
  if      (i < OFF_WSS1) { src = a0; off = OFF_WSW1; }
  else if (i < OFF_WSG1) { src = a1; off = OFF_WSS1; }
  else if (i < OFF_WSC1) { src = a2; off = OFF_WSG1; }
  else if (i < OFF_WSW2) { src = a3; off = OFF_WSC1; }
  else if (i < OFF_WSS2) { src = a4; off = OFF_WSW2; }
  else if (i < OFF_WSG2) { src = a5; off = OFF_WSS2; }
  else if (i < OFF_WSC2) { src = a6; off = OFF_WSG2; }
  else if (i < OFF_WOUT) { src = a7; off = OFF_WSC2; }
  else                   { src = a8; off = OFF_WOUT; }
  out[i] = f2bfu(src[i - off]);
}

template<int KS>
static __device__ __forceinline__ void loadB(const unsigned short* __restrict__ Wrow,
                                             int kb, bf16x8* B)
{
  #pragma unroll
  for (int s = 0; s < KS; ++s) B[s] = *(const bf16x8*)(Wrow + s * 32 + kb);
}

template<int KS>
static __device__ __forceinline__ f32x4 mmA(const unsigned short* lds, int arow,
                                            int kb, const bf16x8* B)
{
  f32x4 acc = {0.f, 0.f, 0.f, 0.f};
  const int xr = (arow & 7) << 3;
  const unsigned short* rp = lds + arow * LSTR;
  #pragma unroll
  for (int s = 0; s < KS; ++s) {
    bf16x8 A = *(const bf16x8*)(rp + ((s * 32 + kb) ^ xr));
    acc = mfma16(A, B[s], acc);
  }
  return acc;
}

// ---------------------------------------------------------------------------
// Main fused kernel. 64 rows/block, 512 threads (8 waves).
// Wave w owns output cols [32w, 32w+32): c in {0,1}, ocol = 32w+16c+(lane&15).
// M-tiles m in {0..3} cover all 64 rows. MFMA 16x16x32 bf16.
// C-layout: col = lane&15, row = 4*(lane>>4) + reg  (m89-verified).
// Phases are sequenced so peak live registers stay under the 128 cap
// (launch_bounds 512,4 -> 2 blocks/CU with exactly 64 KB LDS).
// ---------------------------------------------------------------------------
__global__ __launch_bounds__(THREADS, 4)
void iab_rows_mfma(
    const float* __restrict__ v, const float* __restrict__ af,
    const float* __restrict__ fw, const float* __restrict__ fb,
    const float* __restrict__ ln1g, const float* __restrict__ ln1b,
    const float* __restrict__ bsig1,
    const float* __restrict__ ln2g, const float* __restrict__ ln2b,
    const float* __restrict__ bsig2,
    const float* __restrict__ outb,
    const unsigned short* __restrict__ wc,
    float* __restrict__ scores, int N)
{
  __shared__ __align__(16) unsigned short sA[ROWS * LSTR];  // xhat1 -> x2 -> xhat2 -> xf
  __shared__ __align__(16) unsigned short sB[ROWS * LSTR];  // b1 -> b2

  const unsigned short* Wsw1 = wc + OFF_WSW1;
  const unsigned short* Wss1 = wc + OFF_WSS1;
  const unsigned short* Wsg1 = wc + OFF_WSG1;
  const unsigned short* Wsc1 = wc + OFF_WSC1;
  const unsigned short* Wsw2 = wc + OFF_WSW2;
  const unsigned short* Wss2 = wc + OFF_WSS2;
  const unsigned short* Wsg2 = wc + OFF_WSG2;
  const unsigned short* Wsc2 = wc + OFF_WSC2;
  const unsigned short* Wout = wc + OFF_WOUT;

  const int t    = threadIdx.x;
  const int w    = t >> 6;
  const int lane = t & 63;
  const int cc   = lane & 15;
  const int g4   = lane >> 4;
  const int kb   = g4 * 8;
  const int row0 = blockIdx.x * ROWS;

  // ---- P0: fourier features + concat + LN1 -> sA[rows][0..192) ----
  {
    const float fwl = fw[lane], fbl = fb[lane];
    const float g1a = ln1g[lane], g1b = ln1g[lane + 64], g1c = ln1g[lane + 128];
    const float o1a = ln1b[lane], o1b = ln1b[lane + 64], o1c = ln1b[lane + 128];
    for (int rr = 0; rr < 8; ++rr) {
      const int r = w * 8 + rr;
      const int g = row0 + r;
      float e0 = 0.f, e1 = 0.f, e2 = 0.f;
      if (g < N) {
        const float vx = v[3 * (size_t)g + 0];
        const float vy = v[3 * (size_t)g + 1];
        const float vz = v[3 * (size_t)g + 2];
        const float nrm = sqrtf(vx * vx + vy * vy + vz * vz);
        e0 = __cosf(6.283185307179586f * (nrm * fwl + fbl));
        const float* a = af + (size_t)g * 128;
        e1 = a[lane];
        e2 = a[lane + 64];
      }
      float s  = e0 + e1 + e2;
      float sq = e0 * e0 + e1 * e1 + e2 * e2;
      #pragma unroll
      for (int o = 32; o >= 1; o >>= 1) {
        s  += __shfl_xor(s,  o);
        sq += __shfl_xor(sq, o);
      }
      const float mean = s * (1.f / 192.f);
      const float var  = fmaxf(sq * (1.f / 192.f) - mean * mean, 0.f);
      const float rstd = rsqrtf(var + 1e-5f);
      sA[lidx(r, lane)]       = f2bfu((e0 - mean) * rstd * g1a + o1a);
      sA[lidx(r, lane + 64)]  = f2bfu((e1 - mean) * rstd * g1b + o1b);
      sA[lidx(r, lane + 128)] = f2bfu((e2 - mean) * rstd * g1c + o1c);
    }
  }
  __syncthreads();

  // ---- B1: b1 = silu(x@Wsw1)*(x@Wss1) -> sB  (sw/ss paired, share A reads) ----
  #pragma unroll 1
  for (int c = 0; c < 2; ++c) {
    const int ocol = w * 32 + c * 16 + cc;
    bf16x8 Bw[6], Bs[6];
    loadB<6>(Wsw1 + (size_t)ocol * DIN, kb, Bw);
    loadB<6>(Wss1 + (size_t)ocol * DIN, kb, Bs);
    #pragma unroll
    for (int m = 0; m < 4; ++m) {
      const int arow = m * 16 + cc;
      const int xr = (arow & 7) << 3;
      const unsigned short* rp = sA + arow * LSTR;
      f32x4 aw = {0.f, 0.f, 0.f, 0.f}, as = {0.f, 0.f, 0.f, 0.f};
      #pragma unroll
      for (int s = 0; s < 6; ++s) {
        bf16x8 A = *(const bf16x8*)(rp + ((s * 32 + kb) ^ xr));
        aw = mfma16(A, Bw[s], aw);
        as = mfma16(A, Bs[s], as);
      }
      #pragma unroll
      for (int r = 0; r < 4; ++r) {
        const float u = aw[r];
        sB[lidx(m * 16 + g4 * 4 + r, ocol)] = f2bfu(u * sigm(u) * as[r]);
      }
    }
  }
  __syncthreads();

  // ---- C: x2 = sigmoid(x@Wsg1+b)*(b1@Wsc1) -> packed regs x2p ----
  unsigned x2p[2][4][2];
  #pragma unroll
  for (int c = 0; c < 2; ++c) {
    const int ocol = w * 32 + c * 16 + cc;
    f32x4 aSG[4];
    {
      bf16x8 Bg[6];
      loadB<6>(Wsg1 + (size_t)ocol * DIN, kb, Bg);
      #pragma unroll
      for (int m = 0; m < 4; ++m) aSG[m] = mmA<6>(sA, m * 16 + cc, kb, Bg);
    }
    {
      bf16x8 Bc[8];
      loadB<8>(Wsc1 + (size_t)ocol * HD, kb, Bc);
      const float bias = bsig1[ocol];
      #pragma unroll
      for (int m = 0; m < 4; ++m) {
        f32x4 ac = mmA<8>(sB, m * 16 + cc, kb, Bc);
        const float x0 = sigm(aSG[m][0] + bias) * ac[0];
        const float x1 = sigm(aSG[m][1] + bias) * ac[1];
        const float x2 = sigm(aSG[m][2] + bias) * ac[2];
        const float x3 = sigm(aSG[m][3] + bias) * ac[3];
        x2p[c][m][0] = pk2(x0, x1);
        x2p[c][m][1] = pk2(x2, x3);
      }
    }
  }
  __syncthreads();

  // ---- x2 write: regs -> sA (xhat1 dead) ----
  #pragma unroll
  for (int c = 0; c < 2; ++c) {
    const int ocol = w * 32 + c * 16 + cc;
    #pragma unroll
    for (int m = 0; m < 4; ++m) {
      #pragma unroll
      for (int p = 0; p < 2; ++p) {
        const unsigned pk = x2p[c][m][p];
        sA[lidx(m * 16 + g4 * 4 + 2 * p,     ocol)] = (unsigned short)(pk & 0xffff);
        sA[lidx(m * 16 + g4 * 4 + 2 * p + 1, ocol)] = (unsigned short)(pk >> 16);
      }
    }
  }
  __syncthreads();

  // ---- LN2: in-place on sA (wave-per-row, 8 rows/wave) ----
  {
    float g2[4], o2[4];
    #pragma unroll
    for (int i = 0; i < 4; ++i) { g2[i] = ln2g[lane + 64 * i]; o2[i] = ln2b[lane + 64 * i]; }
    for (int rr = 0; rr < 8; ++rr) {
      const int r = w * 8 + rr;
      float e[4];
      #pragma unroll
      for (int i = 0; i < 4; ++i) e[i] = bfu2f(sA[lidx(r, lane + 64 * i)]);
      float s  = e[0] + e[1] + e[2] + e[3];
      float sq = e[0]*e[0] + e[1]*e[1] + e[2]*e[2] + e[3]*e[3];
      #pragma unroll
      for (int o = 32; o >= 1; o >>= 1) {
        s  += __shfl_xor(s,  o);
        sq += __shfl_xor(sq, o);
      }
      const float mean = s * (1.f / 256.f);
      const float var  = fmaxf(sq * (1.f / 256.f) - mean * mean, 0.f);
      const float rstd = rsqrtf(var + 1e-5f);
      #pragma unroll
      for (int i = 0; i < 4; ++i)
        sA[lidx(r, lane + 64 * i)] = f2bfu((e[i] - mean) * rstd * g2[i] + o2[i]);
    }
  }
  __syncthreads();

  // ---- D1: b2 = silu(xhat2@Wsw2)*(xhat2@Wss2) -> sB (sequential passes) ----
  #pragma unroll 1
  for (int c = 0; c < 2; ++c) {
    const int ocol = w * 32 + c * 16 + cc;
    f32x4 aSW[4];
    {
      bf16x8 Bw[8];
      loadB<8>(Wsw2 + (size_t)ocol * HD, kb, Bw);
      #pragma unroll
      for (int m = 0; m < 4; ++m) aSW[m] = mmA<8>(sA, m * 16 + cc, kb, Bw);
    }
    {
      bf16x8 Bs[8];
      loadB<8>(Wss2 + (size_t)ocol * HD, kb, Bs);
      #pragma unroll
      for (int m = 0; m < 4; ++m) {
        f32x4 as = mmA<8>(sA, m * 16 + cc, kb, Bs);
        #pragma unroll
        for (int r = 0; r < 4; ++r) {
          const float u = aSW[m][r];
          sB[lidx(m * 16 + g4 * 4 + r, ocol)] = f2bfu(u * sigm(u) * as[r]);
        }
      }
    }
  }
  __syncthreads();

  // ---- D23: y = sigmoid(xhat2@Wsg2+b)*(b2@Wsc2); xf = x2 + y -> x2p ----
  #pragma unroll
  for (int c = 0; c < 2; ++c) {
    const int ocol = w * 32 + c * 16 + cc;
    f32x4 aSG[4];
    {
      bf16x8 Bg[8];
      loadB<8>(Wsg2 + (size_t)ocol * HD, kb, Bg);
      #pragma unroll
      for (int m = 0; m < 4; ++m) aSG[m] = mmA<8>(sA, m * 16 + cc, kb, Bg);
    }
    {
      bf16x8 Bc[8];
      loadB<8>(Wsc2 + (size_t)ocol * HD, kb, Bc);
      const float bias = bsig2[ocol];
      #pragma unroll
      for (int m = 0; m < 4; ++m) {
        f32x4 ac = mmA<8>(sB, m * 16 + cc, kb, Bc);
        const float y0 = sigm(aSG[m][0] + bias) * ac[0];
        const float y1 = sigm(aSG[m][1] + bias) * ac[1];
        const float y2 = sigm(aSG[m][2] + bias) * ac[2];
        const float y3 = sigm(aSG[m][3] + bias) * ac[3];
        const float f0 = bfu2f((unsigned short)(x2p[c][m][0] & 0xffff)) + y0;
        const float f1 = bfu2f((unsigned short)(x2p[c][m][0] >> 16))    + y1;
        const float f2 = bfu2f((unsigned short)(x2p[c][m][1] & 0xffff)) + y2;
        const float f3 = bfu2f((unsigned short)(x2p[c][m][1] >> 16))    + y3;
        x2p[c][m][0] = pk2(f0, f1);
        x2p[c][m][1] = pk2(f2, f3);
      }
    }
  }
  __syncthreads();

  // ---- xf write: regs -> sA (xhat2 dead) ----
  #pragma unroll
  for (int c = 0; c < 2; ++c) {
    const int ocol = w * 32 + c * 16 + cc;
    #pragma unroll
    for (int m = 0; m < 4; ++m) {
      #pragma unroll
      for (int p = 0; p < 2; ++p) {
        const unsigned pk = x2p[c][m][p];
        sA[lidx(m * 16 + g4 * 4 + 2 * p,     ocol)] = (unsigned short)(pk & 0xffff);
        sA[lidx(m * 16 + g4 * 4 + 2 * p + 1, ocol)] = (unsigned short)(pk >> 16);
      }
    }
  }
  __syncthreads();

  // ---- F: scores = xf @ out_w.T + out_b ----
  if (t < ROWS * 4) {
    const int r = t >> 2;
    const int h = t & 3;
    const int g = row0 + r;
    if (g < N) {
      float acc = outb[h];
      const int xr = (r & 7) << 3;
      const unsigned short* rp = sA + r * LSTR;
      const unsigned short* wp = Wout + h * HD;
      #pragma unroll
      for (int s = 0; s < 32; ++s) {
        bf16x8 x  = *(const bf16x8*)(rp + ((s * 8) ^ xr));
        bf16x8 ww = *(const bf16x8*)(wp + s * 8);
        #pragma unroll
        for (int j = 0; j < 8; ++j) acc += (float)x[j] * (float)ww[j];
      }
      scores[(size_t)g * 4 + h] = acc;
    }
  }
}

// ---------------------------------------------------------------------------
// Segment softmax + weighted 3-vector pooling (sorted indices, wave/segment).
// ---------------------------------------------------------------------------
__device__ __forceinline__ int iab_lower_bound(const int* __restrict__ a, int n, int key)
{
  int lo = 0, hi = n;
  while (lo < hi) {
    const int mid = (lo + hi) >> 1;
    if (a[mid] < key) lo = mid + 1; else hi = mid;
  }
  return lo;
}

__global__ __launch_bounds__(256)
void iab_segpool_kernel(const float* __restrict__ scores,
                        const float* __restrict__ v,
                        const int* __restrict__ gidx,
                        float* __restrict__ out, int N, int E)
{
  const int seg  = blockIdx.x * 4 + (threadIdx.x >> 6);
  const int lane = threadIdx.x & 63;
  if (seg >= E) return;

  const int lo = iab_lower_bound(gidx, N, seg);
  const int hi = iab_lower_bound(gidx, N, seg + 1);

  const int h  = lane & 3;
  const int ro = lane >> 2;

  float m = -INFINITY;
  for (int base = lo; base < hi; base += 16) {
    const int r = base + ro;
    if (r < hi) m = fmaxf(m, scores[(size_t)r * 4 + h]);
  }
  #pragma unroll
  for (int o = 4; o < 64; o <<= 1) m = fmaxf(m, __shfl_xor(m, o));

  float ssum = 0.f, w0 = 0.f, w1 = 0.f, w2 = 0.f;
  for (int base = lo; base < hi; base += 16) {
    const int r = base + ro;
    if (r < hi) {
      const float e = expf(scores[(size_t)r * 4 + h] - m);
      ssum += e;
      w0 += e * v[3 * (size_t)r + 0];
      w1 += e * v[3 * (size_t)r + 1];
      w2 += e * v[3 * (size_t)r + 2];
    }
  }
  #pragma unroll
  for (int o = 4; o < 64; o <<= 1) {
    ssum += __shfl_xor(ssum, o);
    w0   += __shfl_xor(w0, o);
    w1   += __shfl_xor(w1, o);
    w2   += __shfl_xor(w2, o);
  }

  if (ro == 0) {
    const float inv = (hi > lo) ? (1.f / ssum) : 0.f;
    out[(size_t)seg * 12 + h * 3 + 0] = w0 * inv;
    out[(size_t)seg * 12 + h * 3 + 1] = w1 * inv;
    out[(size_t)seg * 12 + h * 3 + 2] = w2 * inv;
  }
}

// ---------------------------------------------------------------------------
extern "C" void kernel_launch(void* const* d_in, const int* in_sizes, int n_in,
                              void* d_out, int out_size, void* d_ws, size_t ws_size,
                              hipStream_t stream)
{
  const float* v     = (const float*)d_in[0];
  const float* af    = (const float*)d_in[1];
  const int*   gidx  = (const int*)  d_in[2];
  const float* fw    = (const float*)d_in[4];
  const float* fb    = (const float*)d_in[5];
  const float* ln1g  = (const float*)d_in[6];
  const float* ln1b  = (const float*)d_in[7];
  const float* wsw1  = (const float*)d_in[8];
  const float* wss1  = (const float*)d_in[9];
  const float* wsig1 = (const float*)d_in[10];
  const float* bsig1 = (const float*)d_in[11];
  const float* wsc1  = (const float*)d_in[12];
  const float* ln2g  = (const float*)d_in[13];
  const float* ln2b  = (const float*)d_in[14];
  const float* wsw2  = (const float*)d_in[15];
  const float* wss2  = (const float*)d_in[16];
  const float* wsig2 = (const float*)d_in[17];
  const float* bsig2 = (const float*)d_in[18];
  const float* wsc2  = (const float*)d_in[19];
  const float* outw  = (const float*)d_in[20];
  const float* outb  = (const float*)d_in[21];

  const int N = in_sizes[0] / 3;
  const int E = out_size / 12;

  float* scores = (float*)d_ws;                                   // N*4 f32 = 16 MB
  unsigned short* wc = (unsigned short*)((char*)d_ws + (size_t)N * 4 * sizeof(float));

  hipLaunchKernelGGL(iab_wconv_kernel, dim3((W_TOTAL + 255) / 256), dim3(256), 0, stream,
                     wsw1, wss1, wsig1, wsc1, wsw2, wss2, wsig2, wsc2, outw, wc);

  hipLaunchKernelGGL(iab_rows_mfma, dim3((N + ROWS - 1) / ROWS), dim3(THREADS), 0, stream,
                     v, af, fw, fb, ln1g, ln1b, bsig1, ln2g, ln2b, bsig2, outb,
                     wc, scores, N);

  hipLaunchKernelGGL(iab_segpool_kernel, dim3((E + 3) / 4), dim3(256), 0, stream,
                     scores, v, gidx, (float*)d_out, N, E);
}

// Round 4
// 3463.898 us; speedup vs baseline: 1.7290x; 1.7290x over previous
//
#include <hip/hip_runtime.h>
#include <math.h>

#define DIN   192
#define HD    256
#define ROWS  64
#define THREADS 512
#define LSTR  256   // LDS row stride (elems); banking fixed by XOR swizzle

typedef __bf16 bf16_t;
typedef bf16_t bf16x8 __attribute__((ext_vector_type(8)));
typedef float  f32x4  __attribute__((ext_vector_type(4)));

static __device__ __forceinline__ f32x4 mfma16(bf16x8 a, bf16x8 b, f32x4 c) {
  return __builtin_amdgcn_mfma_f32_16x16x32_bf16(a, b, c, 0, 0, 0);
}
static __device__ __forceinline__ unsigned short f2bfu(float f) {
  bf16_t h = (bf16_t)f; unsigned short u; __builtin_memcpy(&u, &h, 2); return u;
}
static __device__ __forceinline__ float bfu2f(unsigned short u) {
  unsigned x = ((unsigned)u) << 16; float f; __builtin_memcpy(&f, &x, 4); return f;
}
static __device__ __forceinline__ unsigned pk2(float a, float b) {
  return (unsigned)f2bfu(a) | ((unsigned)f2bfu(b) << 16);
}
static __device__ __forceinline__ float sigm(float x) {
  return __builtin_amdgcn_rcpf(1.f + __expf(-x));
}
// XOR-swizzled LDS element index (write side / generic)
static __device__ __forceinline__ int lidx(int row, int col) {
  return row * LSTR + (col ^ ((row & 7) << 3));
}
// A-fragment read: row = m*16+cc, k = s*32 + kb + [0..8)
static __device__ __forceinline__ bf16x8 afrag(const unsigned short* buf, int m, int s,
                                               int cc, int kb, int xr) {
  return *(const bf16x8*)(buf + (m * 16 + cc) * LSTR + (((s * 32) + kb) ^ xr));
}

// ---- streaming 4-mtile matmuls, scalar B-fragments only (no arrays!) ----
template<int KS>
static __device__ __forceinline__ void mm4_pair(
    const unsigned short* __restrict__ Wa, const unsigned short* __restrict__ Wb,
    const unsigned short* sIn, int cc, int kb, int xr,
    f32x4& a0, f32x4& a1, f32x4& a2, f32x4& a3,
    f32x4& b0, f32x4& b1, f32x4& b2, f32x4& b3)
{
  #pragma unroll
  for (int s = 0; s < KS; ++s) {
    const bf16x8 ba = *(const bf16x8*)(Wa + s * 32);
    const bf16x8 bb = *(const bf16x8*)(Wb + s * 32);
    bf16x8 A;
    A = afrag(sIn, 0, s, cc, kb, xr); a0 = mfma16(A, ba, a0); b0 = mfma16(A, bb, b0);
    A = afrag(sIn, 1, s, cc, kb, xr); a1 = mfma16(A, ba, a1); b1 = mfma16(A, bb, b1);
    A = afrag(sIn, 2, s, cc, kb, xr); a2 = mfma16(A, ba, a2); b2 = mfma16(A, bb, b2);
    A = afrag(sIn, 3, s, cc, kb, xr); a3 = mfma16(A, ba, a3); b3 = mfma16(A, bb, b3);
  }
}

template<int KS>
static __device__ __forceinline__ void mm4_one(
    const unsigned short* __restrict__ W,
    const unsigned short* sIn, int cc, int kb, int xr,
    f32x4& a0, f32x4& a1, f32x4& a2, f32x4& a3)
{
  #pragma unroll
  for (int s = 0; s < KS; ++s) {
    const bf16x8 bw = *(const bf16x8*)(W + s * 32);
    bf16x8 A;
    A = afrag(sIn, 0, s, cc, kb, xr); a0 = mfma16(A, bw, a0);
    A = afrag(sIn, 1, s, cc, kb, xr); a1 = mfma16(A, bw, a1);
    A = afrag(sIn, 2, s, cc, kb, xr); a2 = mfma16(A, bw, a2);
    A = afrag(sIn, 3, s, cc, kb, xr); a3 = mfma16(A, bw, a3);
  }
}

static __device__ __forceinline__ void silu_store(unsigned short* sOut, int rb, int ocol,
                                                  f32x4 u, f32x4 vv)
{
  #pragma unroll
  for (int r = 0; r < 4; ++r) {
    const float x = u[r];
    sOut[lidx(rb + r, ocol)] = f2bfu(x * sigm(x) * vv[r]);
  }
}

// bf16 weight region layout (elements) inside d_ws after the scores buffer
#define OFF_WSW1 0
#define OFF_WSS1 49152
#define OFF_WSG1 98304
#define OFF_WSC1 147456
#define OFF_WSW2 212992
#define OFF_WSS2 278528
#define OFF_WSG2 344064
#define OFF_WSC2 409600
#define OFF_WOUT 475136
#define W_TOTAL  476160

__global__ void iab_wconv_kernel(const float* __restrict__ a0, const float* __restrict__ a1,
                                 const float* __restrict__ a2, const float* __restrict__ a3,
                                 const float* __restrict__ a4, const float* __restrict__ a5,
                                 const float* __restrict__ a6, const float* __restrict__ a7,
                                 const float* __restrict__ a8, unsigned short* __restrict__ out)
{
  const int i = blockIdx.x * 256 + threadIdx.x;
  if (i >= W_TOTAL) return;
  const float* src; int off;
  if      (i < OFF_WSS1) { src = a0; off = OFF_WSW1; }
  else if (i < OFF_WSG1) { src = a1; off = OFF_WSS1; }
  else if (i < OFF_WSC1) { src = a2; off = OFF_WSG1; }
  else if (i < OFF_WSW2) { src = a3; off = OFF_WSC1; }
  else if (i < OFF_WSS2) { src = a4; off = OFF_WSW2; }
  else if (i < OFF_WSG2) { src = a5; off = OFF_WSS2; }
  else if (i < OFF_WSC2) { src = a6; off = OFF_WSG2; }
  else if (i < OFF_WOUT) { src = a7; off = OFF_WSC2; }
  else                   { src = a8; off = OFF_WOUT; }
  out[i] = f2bfu(src[i - off]);
}

// ---------------------------------------------------------------------------
// Main fused kernel. 64 rows/block, 512 threads (8 waves).
// Wave w owns output cols [32w, 32w+32): two 16-col tiles (c=0,1).
// All per-thread state is named scalars -> nothing for regalloc to demote.
// ---------------------------------------------------------------------------
__global__ __launch_bounds__(THREADS, 2)
void iab_rows_mfma(
    const float* __restrict__ v, const float* __restrict__ af,
    const float* __restrict__ fw, const float* __restrict__ fb,
    const float* __restrict__ ln1g, const float* __restrict__ ln1b,
    const float* __restrict__ bsig1,
    const float* __restrict__ ln2g, const float* __restrict__ ln2b,
    const float* __restrict__ bsig2,
    const float* __restrict__ outb,
    const unsigned short* __restrict__ wc,
    float* __restrict__ scores, int N)
{
  __shared__ __align__(16) unsigned short sA[ROWS * LSTR];  // xhat1 -> x2 -> xhat2 -> xf
  __shared__ __align__(16) unsigned short sB[ROWS * LSTR];  // b1 -> b2

  const unsigned short* Wsw1 = wc + OFF_WSW1;
  const unsigned short* Wss1 = wc + OFF_WSS1;
  const unsigned short* Wsg1 = wc + OFF_WSG1;
  const unsigned short* Wsc1 = wc + OFF_WSC1;
  const unsigned short* Wsw2 = wc + OFF_WSW2;
  const unsigned short* Wss2 = wc + OFF_WSS2;
  const unsigned short* Wsg2 = wc + OFF_WSG2;
  const unsigned short* Wsc2 = wc + OFF_WSC2;
  const unsigned short* Wout = wc + OFF_WOUT;

  const int t    = threadIdx.x;
  const int w    = t >> 6;
  const int lane = t & 63;
  const int cc   = lane & 15;
  const int g4   = lane >> 4;
  const int kb   = g4 * 8;
  const int xr   = (cc & 7) << 3;
  const int row0 = blockIdx.x * ROWS;

  // ---- P0: fourier features + concat + LN1 -> sA[rows][0..192) ----
  {
    const float fwl = fw[lane], fbl = fb[lane];
    const float g1a = ln1g[lane], g1b = ln1g[lane + 64], g1c = ln1g[lane + 128];
    const float o1a = ln1b[lane], o1b = ln1b[lane + 64], o1c = ln1b[lane + 128];
    for (int rr = 0; rr < 8; ++rr) {
      const int r = w * 8 + rr;
      const int g = row0 + r;
      float e0 = 0.f, e1 = 0.f, e2 = 0.f;
      if (g < N) {
        const float vx = v[3 * (size_t)g + 0];
        const float vy = v[3 * (size_t)g + 1];
        const float vz = v[3 * (size_t)g + 2];
        const float nrm = sqrtf(vx * vx + vy * vy + vz * vz);
        e0 = __cosf(6.283185307179586f * (nrm * fwl + fbl));
        const float* a = af + (size_t)g * 128;
        e1 = a[lane];
        e2 = a[lane + 64];
      }
      float s  = e0 + e1 + e2;
      float sq = e0 * e0 + e1 * e1 + e2 * e2;
      #pragma unroll
      for (int o = 32; o >= 1; o >>= 1) {
        s  += __shfl_xor(s,  o);
        sq += __shfl_xor(sq, o);
      }
      const float mean = s * (1.f / 192.f);
      const float var  = fmaxf(sq * (1.f / 192.f) - mean * mean, 0.f);
      const float rstd = rsqrtf(var + 1e-5f);
      sA[lidx(r, lane)]       = f2bfu((e0 - mean) * rstd * g1a + o1a);
      sA[lidx(r, lane + 64)]  = f2bfu((e1 - mean) * rstd * g1b + o1b);
      sA[lidx(r, lane + 128)] = f2bfu((e2 - mean) * rstd * g1c + o1c);
    }
  }
  __syncthreads();

  // ---- B1: b1 = silu(x@Wsw1)*(x@Wss1) -> sB ----
  #pragma unroll 1
  for (int c = 0; c < 2; ++c) {
    const int ocol = w * 32 + c * 16 + cc;
    f32x4 aw0{}, aw1{}, aw2{}, aw3{}, as0{}, as1{}, as2{}, as3{};
    mm4_pair<6>(Wsw1 + (size_t)ocol * DIN + kb, Wss1 + (size_t)ocol * DIN + kb,
                sA, cc, kb, xr, aw0, aw1, aw2, aw3, as0, as1, as2, as3);
    silu_store(sB, 0 * 16 + g4 * 4, ocol, aw0, as0);
    silu_store(sB, 1 * 16 + g4 * 4, ocol, aw1, as1);
    silu_store(sB, 2 * 16 + g4 * 4, ocol, aw2, as2);
    silu_store(sB, 3 * 16 + g4 * 4, ocol, aw3, as3);
  }
  __syncthreads();

  // ---- C: x2 = sigmoid(x@Wsg1+b)*(b1@Wsc1) -> 16 named packed regs ----
  unsigned xa0, xa1, xa2, xa3, xa4, xa5, xa6, xa7;   // c = 0
  unsigned xb0, xb1, xb2, xb3, xb4, xb5, xb6, xb7;   // c = 1
  {
    const int ocol = w * 32 + cc;
    f32x4 g0{}, g1{}, g2{}, g3{};
    mm4_one<6>(Wsg1 + (size_t)ocol * DIN + kb, sA, cc, kb, xr, g0, g1, g2, g3);
    f32x4 c0{}, c1{}, c2{}, c3{};
    mm4_one<8>(Wsc1 + (size_t)ocol * HD + kb, sB, cc, kb, xr, c0, c1, c2, c3);
    const float bias = bsig1[ocol];
    xa0 = pk2(sigm(g0[0] + bias) * c0[0], sigm(g0[1] + bias) * c0[1]);
    xa1 = pk2(sigm(g0[2] + bias) * c0[2], sigm(g0[3] + bias) * c0[3]);
    xa2 = pk2(sigm(g1[0] + bias) * c1[0], sigm(g1[1] + bias) * c1[1]);
    xa3 = pk2(sigm(g1[2] + bias) * c1[2], sigm(g1[3] + bias) * c1[3]);
    xa4 = pk2(sigm(g2[0] + bias) * c2[0], sigm(g2[1] + bias) * c2[1]);
    xa5 = pk2(sigm(g2[2] + bias) * c2[2], sigm(g2[3] + bias) * c2[3]);
    xa6 = pk2(sigm(g3[0] + bias) * c3[0], sigm(g3[1] + bias) * c3[1]);
    xa7 = pk2(sigm(g3[2] + bias) * c3[2], sigm(g3[3] + bias) * c3[3]);
  }
  __builtin_amdgcn_sched_barrier(0);
  {
    const int ocol = w * 32 + 16 + cc;
    f32x4 g0{}, g1{}, g2{}, g3{};
    mm4_one<6>(Wsg1 + (size_t)ocol * DIN + kb, sA, cc, kb, xr, g0, g1, g2, g3);
    f32x4 c0{}, c1{}, c2{}, c3{};
    mm4_one<8>(Wsc1 + (size_t)ocol * HD + kb, sB, cc, kb, xr, c0, c1, c2, c3);
    const float bias = bsig1[ocol];
    xb0 = pk2(sigm(g0[0] + bias) * c0[0], sigm(g0[1] + bias) * c0[1]);
    xb1 = pk2(sigm(g0[2] + bias) * c0[2], sigm(g0[3] + bias) * c0[3]);
    xb2 = pk2(sigm(g1[0] + bias) * c1[0], sigm(g1[1] + bias) * c1[1]);
    xb3 = pk2(sigm(g1[2] + bias) * c1[2], sigm(g1[3] + bias) * c1[3]);
    xb4 = pk2(sigm(g2[0] + bias) * c2[0], sigm(g2[1] + bias) * c2[1]);
    xb5 = pk2(sigm(g2[2] + bias) * c2[2], sigm(g2[3] + bias) * c2[3]);
    xb6 = pk2(sigm(g3[0] + bias) * c3[0], sigm(g3[1] + bias) * c3[1]);
    xb7 = pk2(sigm(g3[2] + bias) * c3[2], sigm(g3[3] + bias) * c3[3]);
  }
  __syncthreads();

  // ---- x2 write: named regs -> sA (xhat1 dead) ----
  {
    const int oc0 = w * 32 + cc, oc1 = oc0 + 16, rb = g4 * 4;
    #define X2W(dst, PK, M, P) \
      sA[lidx((M) * 16 + rb + 2 * (P),     dst)] = (unsigned short)((PK) & 0xffff); \
      sA[lidx((M) * 16 + rb + 2 * (P) + 1, dst)] = (unsigned short)((PK) >> 16);
    X2W(oc0, xa0, 0, 0) X2W(oc0, xa1, 0, 1) X2W(oc0, xa2, 1, 0) X2W(oc0, xa3, 1, 1)
    X2W(oc0, xa4, 2, 0) X2W(oc0, xa5, 2, 1) X2W(oc0, xa6, 3, 0) X2W(oc0, xa7, 3, 1)
    X2W(oc1, xb0, 0, 0) X2W(oc1, xb1, 0, 1) X2W(oc1, xb2, 1, 0) X2W(oc1, xb3, 1, 1)
    X2W(oc1, xb4, 2, 0) X2W(oc1, xb5, 2, 1) X2W(oc1, xb6, 3, 0) X2W(oc1, xb7, 3, 1)
  }
  __syncthreads();

  // ---- LN2: in-place on sA (wave-per-row, 8 rows/wave) ----
  {
    float g2v[4], o2v[4];
    #pragma unroll
    for (int i = 0; i < 4; ++i) { g2v[i] = ln2g[lane + 64 * i]; o2v[i] = ln2b[lane + 64 * i]; }
    for (int rr = 0; rr < 8; ++rr) {
      const int r = w * 8 + rr;
      float e[4];
      #pragma unroll
      for (int i = 0; i < 4; ++i) e[i] = bfu2f(sA[lidx(r, lane + 64 * i)]);
      float s  = e[0] + e[1] + e[2] + e[3];
      float sq = e[0]*e[0] + e[1]*e[1] + e[2]*e[2] + e[3]*e[3];
      #pragma unroll
      for (int o = 32; o >= 1; o >>= 1) {
        s  += __shfl_xor(s,  o);
        sq += __shfl_xor(sq, o);
      }
      const float mean = s * (1.f / 256.f);
      const float var  = fmaxf(sq * (1.f / 256.f) - mean * mean, 0.f);
      const float rstd = rsqrtf(var + 1e-5f);
      #pragma unroll
      for (int i = 0; i < 4; ++i)
        sA[lidx(r, lane + 64 * i)] = f2bfu((e[i] - mean) * rstd * g2v[i] + o2v[i]);
    }
  }
  __syncthreads();

  // ---- D1: b2 = silu(xhat2@Wsw2)*(xhat2@Wss2) -> sB ----
  #pragma unroll 1
  for (int c = 0; c < 2; ++c) {
    const int ocol = w * 32 + c * 16 + cc;
    f32x4 aw0{}, aw1{}, aw2{}, aw3{}, as0{}, as1{}, as2{}, as3{};
    mm4_pair<8>(Wsw2 + (size_t)ocol * HD + kb, Wss2 + (size_t)ocol * HD + kb,
                sA, cc, kb, xr, aw0, aw1, aw2, aw3, as0, as1, as2, as3);
    silu_store(sB, 0 * 16 + g4 * 4, ocol, aw0, as0);
    silu_store(sB, 1 * 16 + g4 * 4, ocol, aw1, as1);
    silu_store(sB, 2 * 16 + g4 * 4, ocol, aw2, as2);
    silu_store(sB, 3 * 16 + g4 * 4, ocol, aw3, as3);
  }
  __syncthreads();

  // ---- D23: y = sigmoid(xhat2@Wsg2+b)*(b2@Wsc2); xf = x2 + y (in regs) ----
  {
    const int ocol = w * 32 + cc;
    f32x4 g0{}, g1{}, g2{}, g3{};
    mm4_one<8>(Wsg2 + (size_t)ocol * HD + kb, sA, cc, kb, xr, g0, g1, g2, g3);
    f32x4 c0{}, c1{}, c2{}, c3{};
    mm4_one<8>(Wsc2 + (size_t)ocol * HD + kb, sB, cc, kb, xr, c0, c1, c2, c3);
    const float bias = bsig2[ocol];
    #define RESPK(PK, G, C, I0, I1) \
      PK = pk2(bfu2f((unsigned short)((PK) & 0xffff)) + sigm(G[I0] + bias) * C[I0], \
               bfu2f((unsigned short)((PK) >> 16))    + sigm(G[I1] + bias) * C[I1]);
    RESPK(xa0, g0, c0, 0, 1) RESPK(xa1, g0, c0, 2, 3)
    RESPK(xa2, g1, c1, 0, 1) RESPK(xa3, g1, c1, 2, 3)
    RESPK(xa4, g2, c2, 0, 1) RESPK(xa5, g2, c2, 2, 3)
    RESPK(xa6, g3, c3, 0, 1) RESPK(xa7, g3, c3, 2, 3)
  }
  __builtin_amdgcn_sched_barrier(0);
  {
    const int ocol = w * 32 + 16 + cc;
    f32x4 g0{}, g1{}, g2{}, g3{};
    mm4_one<8>(Wsg2 + (size_t)ocol * HD + kb, sA, cc, kb, xr, g0, g1, g2, g3);
    f32x4 c0{}, c1{}, c2{}, c3{};
    mm4_one<8>(Wsc2 + (size_t)ocol * HD + kb, sB, cc, kb, xr, c0, c1, c2, c3);
    const float bias = bsig2[ocol];
    RESPK(xb0, g0, c0, 0, 1) RESPK(xb1, g0, c0, 2, 3)
    RESPK(xb2, g1, c1, 0, 1) RESPK(xb3, g1, c1, 2, 3)
    RESPK(xb4, g2, c2, 0, 1) RESPK(xb5, g2, c2, 2, 3)
    RESPK(xb6, g3, c3, 0, 1) RESPK(xb7, g3, c3, 2, 3)
  }
  __syncthreads();

  // ---- xf write: named regs -> sA (xhat2 dead) ----
  {
    const int oc0 = w * 32 + cc, oc1 = oc0 + 16, rb = g4 * 4;
    X2W(oc0, xa0, 0, 0) X2W(oc0, xa1, 0, 1) X2W(oc0, xa2, 1, 0) X2W(oc0, xa3, 1, 1)
    X2W(oc0, xa4, 2, 0) X2W(oc0, xa5, 2, 1) X2W(oc0, xa6, 3, 0) X2W(oc0, xa7, 3, 1)
    X2W(oc1, xb0, 0, 0) X2W(oc1, xb1, 0, 1) X2W(oc1, xb2, 1, 0) X2W(oc1, xb3, 1, 1)
    X2W(oc1, xb4, 2, 0) X2W(oc1, xb5, 2, 1) X2W(oc1, xb6, 3, 0) X2W(oc1, xb7, 3, 1)
  }
  __syncthreads();

  // ---- F: scores = xf @ out_w.T + out_b ----
  if (t < ROWS * 4) {
    const int r = t >> 2;
    const int h = t & 3;
    const int g = row0 + r;
    if (g < N) {
      float acc = outb[h];
      const int xrr = (r & 7) << 3;
      const unsigned short* rp = sA + r * LSTR;
      const unsigned short* wp = Wout + h * HD;
      #pragma unroll
      for (int s = 0; s < 32; ++s) {
        bf16x8 x  = *(const bf16x8*)(rp + ((s * 8) ^ xrr));
        bf16x8 ww = *(const bf16x8*)(wp + s * 8);
        #pragma unroll
        for (int j = 0; j < 8; ++j) acc += (float)x[j] * (float)ww[j];
      }
      scores[(size_t)g * 4 + h] = acc;
    }
  }
}

// ---------------------------------------------------------------------------
// Segment softmax + weighted 3-vector pooling (sorted indices, wave/segment).
// ---------------------------------------------------------------------------
__device__ __forceinline__ int iab_lower_bound(const int* __restrict__ a, int n, int key)
{
  int lo = 0, hi = n;
  while (lo < hi) {
    const int mid = (lo + hi) >> 1;
    if (a[mid] < key) lo = mid + 1; else hi = mid;
  }
  return lo;
}

__global__ __launch_bounds__(256)
void iab_segpool_kernel(const float* __restrict__ scores,
                        const float* __restrict__ v,
                        const int* __restrict__ gidx,
                        float* __restrict__ out, int N, int E)
{
  const int seg  = blockIdx.x * 4 + (threadIdx.x >> 6);
  const int lane = threadIdx.x & 63;
  if (seg >= E) return;

  const int lo = iab_lower_bound(gidx, N, seg);
  const int hi = iab_lower_bound(gidx, N, seg + 1);

  const int h  = lane & 3;
  const int ro = lane >> 2;

  float m = -INFINITY;
  for (int base = lo; base < hi; base += 16) {
    const int r = base + ro;
    if (r < hi) m = fmaxf(m, scores[(size_t)r * 4 + h]);
  }
  #pragma unroll
  for (int o = 4; o < 64; o <<= 1) m = fmaxf(m, __shfl_xor(m, o));

  float ssum = 0.f, w0 = 0.f, w1 = 0.f, w2 = 0.f;
  for (int base = lo; base < hi; base += 16) {
    const int r = base + ro;
    if (r < hi) {
      const float e = expf(scores[(size_t)r * 4 + h] - m);
      ssum += e;
      w0 += e * v[3 * (size_t)r + 0];
      w1 += e * v[3 * (size_t)r + 1];
      w2 += e * v[3 * (size_t)r + 2];
    }
  }
  #pragma unroll
  for (int o = 4; o < 64; o <<= 1) {
    ssum += __shfl_xor(ssum, o);
    w0   += __shfl_xor(w0, o);
    w1   += __shfl_xor(w1, o);
    w2   += __shfl_xor(w2, o);
  }

  if (ro == 0) {
    const float inv = (hi > lo) ? (1.f / ssum) : 0.f;
    out[(size_t)seg * 12 + h * 3 + 0] = w0 * inv;
    out[(size_t)seg * 12 + h * 3 + 1] = w1 * inv;
    out[(size_t)seg * 12 + h * 3 + 2] = w2 * inv;
  }
}

// ---------------------------------------------------------------------------
extern "C" void kernel_launch(void* const* d_in, const int* in_sizes, int n_in,
                              void* d_out, int out_size, void* d_ws, size_t ws_size,
                              hipStream_t stream)
{
  const float* v     = (const float*)d_in[0];
  const float* af    = (const float*)d_in[1];
  const int*   gidx  = (const int*)  d_in[2];
  const float* fw    = (const float*)d_in[4];
  const float* fb    = (const float*)d_in[5];
  const float* ln1g  = (const float*)d_in[6];
  const float* ln1b  = (const float*)d_in[7];
  const float* wsw1  = (const float*)d_in[8];
  const float* wss1  = (const float*)d_in[9];
  const float* wsig1 = (const float*)d_in[10];
  const float* bsig1 = (const float*)d_in[11];
  const float* wsc1  = (const float*)d_in[12];
  const float* ln2g  = (const float*)d_in[13];
  const float* ln2b  = (const float*)d_in[14];
  const float* wsw2  = (const float*)d_in[15];
  const float* wss2  = (const float*)d_in[16];
  const float* wsig2 = (const float*)d_in[17];
  const float* bsig2 = (const float*)d_in[18];
  const float* wsc2  = (const float*)d_in[19];
  const float* outw  = (const float*)d_in[20];
  const float* outb  = (const float*)d_in[21];

  const int N = in_sizes[0] / 3;
  const int E = out_size / 12;

  float* scores = (float*)d_ws;                                   // N*4 f32 = 16 MB
  unsigned short* wc = (unsigned short*)((char*)d_ws + (size_t)N * 4 * sizeof(float));

  hipLaunchKernelGGL(iab_wconv_kernel, dim3((W_TOTAL + 255) / 256), dim3(256), 0, stream,
                     wsw1, wss1, wsig1, wsc1, wsw2, wss2, wsig2, wsc2, outw, wc);

  hipLaunchKernelGGL(iab_rows_mfma, dim3((N + ROWS - 1) / ROWS), dim3(THREADS), 0, stream,
                     v, af, fw, fb, ln1g, ln1b, bsig1, ln2g, ln2b, bsig2, outb,
                     wc, scores, N);

  hipLaunchKernelGGL(iab_segpool_kernel, dim3((E + 3) / 4), dim3(256), 0, stream,
                     scores, v, gidx, (float*)d_out, N, E);
}

// Round 5
// 2057.503 us; speedup vs baseline: 2.9109x; 1.6835x over previous
//
#include <hip/hip_runtime.h>
#include <math.h>

#define DIN   192
#define HD    256
#define ROWS  64
#define THREADS 512
#define LSTR  256

typedef __bf16 bf16_t;
typedef bf16_t bf16x8 __attribute__((ext_vector_type(8)));
typedef float  f32x16 __attribute__((ext_vector_type(16)));

static __device__ __forceinline__ f32x16 mfma32(bf16x8 a, bf16x8 b, f32x16 c) {
  return __builtin_amdgcn_mfma_f32_32x32x16_bf16(a, b, c, 0, 0, 0);
}
static __device__ __forceinline__ unsigned short f2bfu(float f) {
  bf16_t h = (bf16_t)f; unsigned short u; __builtin_memcpy(&u, &h, 2); return u;
}
static __device__ __forceinline__ float bfu2f(unsigned short u) {
  unsigned x = ((unsigned)u) << 16; float f; __builtin_memcpy(&f, &x, 4); return f;
}
static __device__ __forceinline__ unsigned pk2(float a, float b) {
  return (unsigned)f2bfu(a) | ((unsigned)f2bfu(b) << 16);
}
static __device__ __forceinline__ float lo16(unsigned u) { return bfu2f((unsigned short)(u & 0xffff)); }
static __device__ __forceinline__ float hi16(unsigned u) { return bfu2f((unsigned short)(u >> 16)); }
static __device__ __forceinline__ float sigm(float x) {
  return __builtin_amdgcn_rcpf(1.f + __expf(-x));
}
// XOR-swizzled LDS element index
static __device__ __forceinline__ int lidx(int row, int col) {
  return row * LSTR + (col ^ ((row & 7) << 3));
}
// C-layout row for 32x32 MFMA (m74/m101): row = (r&3) + 8*(r>>2) + 4*kg
static __device__ __forceinline__ int crow(int r, int kg) {
  return (r & 3) + 8 * (r >> 2) + 4 * kg;
}

// bf16 weight regions (elements) inside d_ws after the scores buffer.
// All big matrices stored in MFMA-B-fragment order: ((tile*KS + ks)*64 + lane)*8 + j
// where tile=ocol>>5, lane=kg*32+(ocol&31), k = ks*16 + kg*8 + j.
#define OFF_WSW1 0
#define OFF_WSS1 49152
#define OFF_WSG1 98304
#define OFF_WSC1 147456
#define OFF_WSW2 212992
#define OFF_WSS2 278528
#define OFF_WSG2 344064
#define OFF_WSC2 409600
#define OFF_WOUT 475136     // out_w kept linear [4][256]
#define NGRP_REORD 59392    // 3*6144 + 5*8192 groups of 8
#define NGRP_ALL   59520    // + 128 groups for out_w

__global__ void iab_wconv_kernel(const float* __restrict__ a0, const float* __restrict__ a1,
                                 const float* __restrict__ a2, const float* __restrict__ a3,
                                 const float* __restrict__ a4, const float* __restrict__ a5,
                                 const float* __restrict__ a6, const float* __restrict__ a7,
                                 const float* __restrict__ a8, unsigned short* __restrict__ out)
{
  const int i = blockIdx.x * 256 + threadIdx.x;
  if (i >= NGRP_ALL) return;
  if (i >= NGRP_REORD) {                       // out_w linear copy
    const int g = i - NGRP_REORD;
    #pragma unroll
    for (int j = 0; j < 8; ++j) out[OFF_WOUT + g * 8 + j] = f2bfu(a8[g * 8 + j]);
    return;
  }
  const float* src; int off, Kd, g;
  if      (i < 6144)  { src = a0; off = OFF_WSW1; Kd = 192; g = i; }
  else if (i < 12288) { src = a1; off = OFF_WSS1; Kd = 192; g = i - 6144; }
  else if (i < 18432) { src = a2; off = OFF_WSG1; Kd = 192; g = i - 12288; }
  else if (i < 26624) { src = a3; off = OFF_WSC1; Kd = 256; g = i - 18432; }
  else if (i < 34816) { src = a4; off = OFF_WSW2; Kd = 256; g = i - 26624; }
  else if (i < 43008) { src = a5; off = OFF_WSS2; Kd = 256; g = i - 34816; }
  else if (i < 51200) { src = a6; off = OFF_WSG2; Kd = 256; g = i - 43008; }
  else                { src = a7; off = OFF_WSC2; Kd = 256; g = i - 51200; }
  const int KS   = Kd >> 4;
  const int tile = g / (KS * 64);
  const int rem  = g - tile * (KS * 64);
  const int ks   = rem >> 6;
  const int ln   = rem & 63;
  const float* sp = src + (size_t)(tile * 32 + (ln & 31)) * Kd + ks * 16 + (ln >> 5) * 8;
  #pragma unroll
  for (int j = 0; j < 8; ++j) out[off + (size_t)g * 8 + j] = f2bfu(sp[j]);
}

// GEMM pass: one weight matrix, both 32-row m-tiles, shared W stream.
// Wt pre-offset to (w*KS*64 + lane)*8; ks step advances 512 elements.
template<int KS>
static __device__ __forceinline__ void gemm2(const unsigned short* __restrict__ Wt,
                                             const unsigned short* __restrict__ sIn,
                                             int l31, int kg, int xr,
                                             f32x16& acc0, f32x16& acc1)
{
  #pragma unroll 4
  for (int ks = 0; ks < KS; ++ks) {
    const bf16x8 Wc = *(const bf16x8*)(Wt + ks * 512);
    const int col = (ks * 16 + kg * 8) ^ xr;
    const bf16x8 A0 = *(const bf16x8*)(sIn + l31 * LSTR + col);
    const bf16x8 A1 = *(const bf16x8*)(sIn + (l31 + 32) * LSTR + col);
    acc0 = mfma32(A0, Wc, acc0);
    acc1 = mfma32(A1, Wc, acc1);
  }
}

// pack two f32x16 accumulators into 16 bf16x2 words (pairs of adjacent regs)
static __device__ __forceinline__ void pack32(const f32x16 a0, const f32x16 a1, unsigned* up)
{
  #pragma unroll
  for (int p = 0; p < 8; ++p) up[p]     = pk2(a0[2 * p], a0[2 * p + 1]);
  #pragma unroll
  for (int p = 0; p < 8; ++p) up[8 + p] = pk2(a1[2 * p], a1[2 * p + 1]);
}

// b = silu(u) * s  -> bf16 LDS (one m-tile)
static __device__ __forceinline__ void storeSilu(unsigned short* dst, const unsigned* up,
                                                 const f32x16 s, int mt, int kg, int ocol)
{
  #pragma unroll
  for (int p = 0; p < 8; ++p) {
    const float ua = lo16(up[p]), ub = hi16(up[p]);
    const int r0 = 2 * p;
    const int row0 = mt * 32 + crow(r0, kg);
    dst[lidx(row0,     ocol)] = f2bfu(ua * sigm(ua) * s[r0]);
    dst[lidx(row0 + 1, ocol)] = f2bfu(ub * sigm(ub) * s[r0 + 1]);
  }
}

// write 16 packed words (2 m-tiles) to LDS
static __device__ __forceinline__ void storePk(unsigned short* dst, const unsigned* xp,
                                               int kg, int ocol)
{
  #pragma unroll
  for (int mt = 0; mt < 2; ++mt) {
    #pragma unroll
    for (int p = 0; p < 8; ++p) {
      const int r0 = 2 * p;
      const int row0 = mt * 32 + crow(r0, kg);
      const unsigned pk = xp[mt * 8 + p];
      dst[lidx(row0,     ocol)] = (unsigned short)(pk & 0xffff);
      dst[lidx(row0 + 1, ocol)] = (unsigned short)(pk >> 16);
    }
  }
}

// ---------------------------------------------------------------------------
// Main fused kernel. 64 rows/block, 512 threads (8 waves).
// Wave w owns ocols [32w, 32w+32); 2 m-tiles of 32 rows. 32x32x16 MFMA.
// Single-matrix GEMM passes, packed-bf16 carried intermediates: peak ~105 regs.
// ---------------------------------------------------------------------------
__global__ __launch_bounds__(THREADS, 2)
void iab_rows_mfma(
    const float* __restrict__ v, const float* __restrict__ af,
    const float* __restrict__ fw, const float* __restrict__ fb,
    const float* __restrict__ ln1g, const float* __restrict__ ln1b,
    const float* __restrict__ bsig1,
    const float* __restrict__ ln2g, const float* __restrict__ ln2b,
    const float* __restrict__ bsig2,
    const float* __restrict__ outb,
    const unsigned short* __restrict__ wc,
    float* __restrict__ scores, int N)
{
  __shared__ __align__(16) unsigned short sA[ROWS * LSTR];  // xhat1 -> x2 -> xhat2 -> xf
  __shared__ __align__(16) unsigned short sB[ROWS * LSTR];  // b1 -> b2

  const int t    = threadIdx.x;
  const int w    = t >> 6;
  const int lane = t & 63;
  const int l31  = lane & 31;
  const int kg   = lane >> 5;
  const int xr   = (lane & 7) << 3;     // row&7 == lane&7 for both m-tiles
  const int ocol = w * 32 + l31;
  const int row0 = blockIdx.x * ROWS;

  // per-matrix W' stream base for this wave/lane
  const unsigned short* WtSW1 = wc + OFF_WSW1 + (w * 12 * 64 + lane) * 8;
  const unsigned short* WtSS1 = wc + OFF_WSS1 + (w * 12 * 64 + lane) * 8;
  const unsigned short* WtSG1 = wc + OFF_WSG1 + (w * 12 * 64 + lane) * 8;
  const unsigned short* WtSC1 = wc + OFF_WSC1 + (w * 16 * 64 + lane) * 8;
  const unsigned short* WtSW2 = wc + OFF_WSW2 + (w * 16 * 64 + lane) * 8;
  const unsigned short* WtSS2 = wc + OFF_WSS2 + (w * 16 * 64 + lane) * 8;
  const unsigned short* WtSG2 = wc + OFF_WSG2 + (w * 16 * 64 + lane) * 8;
  const unsigned short* WtSC2 = wc + OFF_WSC2 + (w * 16 * 64 + lane) * 8;

  // ---- P0: fourier features + concat + LN1 -> sA ----
  {
    const float fwl = fw[lane], fbl = fb[lane];
    const float g1a = ln1g[lane], g1b = ln1g[lane + 64], g1c = ln1g[lane + 128];
    const float o1a = ln1b[lane], o1b = ln1b[lane + 64], o1c = ln1b[lane + 128];
    for (int rr = 0; rr < 8; ++rr) {
      const int r = w * 8 + rr;
      const int g = row0 + r;
      float e0 = 0.f, e1 = 0.f, e2 = 0.f;
      if (g < N) {
        const float vx = v[3 * (size_t)g + 0];
        const float vy = v[3 * (size_t)g + 1];
        const float vz = v[3 * (size_t)g + 2];
        const float nrm = sqrtf(vx * vx + vy * vy + vz * vz);
        e0 = __cosf(6.283185307179586f * (nrm * fwl + fbl));
        const float* a = af + (size_t)g * 128;
        e1 = a[lane];
        e2 = a[lane + 64];
      }
      float s  = e0 + e1 + e2;
      float sq = e0 * e0 + e1 * e1 + e2 * e2;
      #pragma unroll
      for (int o = 32; o >= 1; o >>= 1) {
        s  += __shfl_xor(s,  o);
        sq += __shfl_xor(sq, o);
      }
      const float mean = s * (1.f / 192.f);
      const float var  = fmaxf(sq * (1.f / 192.f) - mean * mean, 0.f);
      const float rstd = rsqrtf(var + 1e-5f);
      sA[lidx(r, lane)]       = f2bfu((e0 - mean) * rstd * g1a + o1a);
      sA[lidx(r, lane + 64)]  = f2bfu((e1 - mean) * rstd * g1b + o1b);
      sA[lidx(r, lane + 128)] = f2bfu((e2 - mean) * rstd * g1c + o1c);
    }
  }
  __syncthreads();

  unsigned x2p[16];   // packed x2 (TB1 out), carried to TB2 residual

  // ---- B1a: u = xhat1 @ Wsw1^T ----
  {
    unsigned up[16];
    {
      f32x16 u0{}, u1{};
      gemm2<12>(WtSW1, sA, l31, kg, xr, u0, u1);
      pack32(u0, u1, up);
    }
    // ---- B1b: s = xhat1 @ Wss1^T; b1 = silu(u)*s -> sB ----
    f32x16 s0{}, s1{};
    gemm2<12>(WtSS1, sA, l31, kg, xr, s0, s1);
    storeSilu(sB, up,     s0, 0, kg, ocol);
    storeSilu(sB, up + 8, s1, 1, kg, ocol);
  }

  // ---- C-sg: sig = sigmoid(xhat1 @ Wsg1^T + b)  (reads sA only; pre-barrier) ----
  unsigned sgp[16];
  {
    f32x16 g0{}, g1{};
    gemm2<12>(WtSG1, sA, l31, kg, xr, g0, g1);
    const float bias = bsig1[ocol];
    #pragma unroll
    for (int p = 0; p < 8; ++p) {
      sgp[p]     = pk2(sigm(g0[2*p] + bias), sigm(g0[2*p+1] + bias));
      sgp[8 + p] = pk2(sigm(g1[2*p] + bias), sigm(g1[2*p+1] + bias));
    }
  }
  __syncthreads();   // b1 visible; all sA (xhat1) reads complete

  // ---- C-sc: c = b1 @ Wsc1^T; x2 = sig * c -> regs + sA ----
  {
    f32x16 c0{}, c1{};
    gemm2<16>(WtSC1, sB, l31, kg, xr, c0, c1);
    #pragma unroll
    for (int p = 0; p < 8; ++p) {
      x2p[p]     = pk2(lo16(sgp[p]) * c0[2*p],     hi16(sgp[p]) * c0[2*p+1]);
      x2p[8 + p] = pk2(lo16(sgp[8+p]) * c1[2*p],   hi16(sgp[8+p]) * c1[2*p+1]);
    }
    storePk(sA, x2p, kg, ocol);   // x2 -> sA (xhat1 dead)
  }
  __syncthreads();

  // ---- LN2: in-place on sA ----
  {
    float g2v[4], o2v[4];
    #pragma unroll
    for (int i = 0; i < 4; ++i) { g2v[i] = ln2g[lane + 64 * i]; o2v[i] = ln2b[lane + 64 * i]; }
    for (int rr = 0; rr < 8; ++rr) {
      const int r = w * 8 + rr;
      float e[4];
      #pragma unroll
      for (int i = 0; i < 4; ++i) e[i] = bfu2f(sA[lidx(r, lane + 64 * i)]);
      float s  = e[0] + e[1] + e[2] + e[3];
      float sq = e[0]*e[0] + e[1]*e[1] + e[2]*e[2] + e[3]*e[3];
      #pragma unroll
      for (int o = 32; o >= 1; o >>= 1) {
        s  += __shfl_xor(s,  o);
        sq += __shfl_xor(sq, o);
      }
      const float mean = s * (1.f / 256.f);
      const float var  = fmaxf(sq * (1.f / 256.f) - mean * mean, 0.f);
      const float rstd = rsqrtf(var + 1e-5f);
      #pragma unroll
      for (int i = 0; i < 4; ++i)
        sA[lidx(r, lane + 64 * i)] = f2bfu((e[i] - mean) * rstd * g2v[i] + o2v[i]);
    }
  }
  __syncthreads();

  // ---- D1a: u2 = xhat2 @ Wsw2^T ----
  {
    unsigned up[16];
    {
      f32x16 u0{}, u1{};
      gemm2<16>(WtSW2, sA, l31, kg, xr, u0, u1);
      pack32(u0, u1, up);
    }
    // ---- D1b: s2 = xhat2 @ Wss2^T; b2 = silu(u2)*s2 -> sB ----
    f32x16 s0{}, s1{};
    gemm2<16>(WtSS2, sA, l31, kg, xr, s0, s1);
    storeSilu(sB, up,     s0, 0, kg, ocol);
    storeSilu(sB, up + 8, s1, 1, kg, ocol);
  }

  // ---- D23-sg: sig2 = sigmoid(xhat2 @ Wsg2^T + b)  (pre-barrier) ----
  {
    f32x16 g0{}, g1{};
    gemm2<16>(WtSG2, sA, l31, kg, xr, g0, g1);
    const float bias = bsig2[ocol];
    #pragma unroll
    for (int p = 0; p < 8; ++p) {
      sgp[p]     = pk2(sigm(g0[2*p] + bias), sigm(g0[2*p+1] + bias));
      sgp[8 + p] = pk2(sigm(g1[2*p] + bias), sigm(g1[2*p+1] + bias));
    }
  }
  __syncthreads();   // b2 visible; all sA (xhat2) reads complete

  // ---- D23-sc: c2 = b2 @ Wsc2^T; xf = x2 + sig2*c2 -> sA ----
  {
    f32x16 c0{}, c1{};
    gemm2<16>(WtSC2, sB, l31, kg, xr, c0, c1);
    #pragma unroll
    for (int p = 0; p < 8; ++p) {
      x2p[p]     = pk2(lo16(x2p[p])   + lo16(sgp[p])   * c0[2*p],
                       hi16(x2p[p])   + hi16(sgp[p])   * c0[2*p+1]);
      x2p[8 + p] = pk2(lo16(x2p[8+p]) + lo16(sgp[8+p]) * c1[2*p],
                       hi16(x2p[8+p]) + hi16(sgp[8+p]) * c1[2*p+1]);
    }
    storePk(sA, x2p, kg, ocol);
  }
  __syncthreads();

  // ---- F: scores = xf @ out_w^T + out_b ----
  if (t < ROWS * 4) {
    const int r = t >> 2;
    const int h = t & 3;
    const int g = row0 + r;
    if (g < N) {
      float acc = outb[h];
      const int xrr = (r & 7) << 3;
      const unsigned short* rp = sA + r * LSTR;
      const unsigned short* wp = wc + OFF_WOUT + h * HD;
      #pragma unroll
      for (int s = 0; s < 32; ++s) {
        bf16x8 x  = *(const bf16x8*)(rp + ((s * 8) ^ xrr));
        bf16x8 ww = *(const bf16x8*)(wp + s * 8);
        #pragma unroll
        for (int j = 0; j < 8; ++j) acc += (float)x[j] * (float)ww[j];
      }
      scores[(size_t)g * 4 + h] = acc;
    }
  }
}

// ---------------------------------------------------------------------------
// Segment softmax + weighted 3-vector pooling (sorted indices, wave/segment).
// ---------------------------------------------------------------------------
__device__ __forceinline__ int iab_lower_bound(const int* __restrict__ a, int n, int key)
{
  int lo = 0, hi = n;
  while (lo < hi) {
    const int mid = (lo + hi) >> 1;
    if (a[mid] < key) lo = mid + 1; else hi = mid;
  }
  return lo;
}

__global__ __launch_bounds__(256)
void iab_segpool_kernel(const float* __restrict__ scores,
                        const float* __restrict__ v,
                        const int* __restrict__ gidx,
                        float* __restrict__ out, int N, int E)
{
  const int seg  = blockIdx.x * 4 + (threadIdx.x >> 6);
  const int lane = threadIdx.x & 63;
  if (seg >= E) return;

  const int lo = iab_lower_bound(gidx, N, seg);
  const int hi = iab_lower_bound(gidx, N, seg + 1);

  const int h  = lane & 3;
  const int ro = lane >> 2;

  float m = -INFINITY;
  for (int base = lo; base < hi; base += 16) {
    const int r = base + ro;
    if (r < hi) m = fmaxf(m, scores[(size_t)r * 4 + h]);
  }
  #pragma unroll
  for (int o = 4; o < 64; o <<= 1) m = fmaxf(m, __shfl_xor(m, o));

  float ssum = 0.f, w0 = 0.f, w1 = 0.f, w2 = 0.f;
  for (int base = lo; base < hi; base += 16) {
    const int r = base + ro;
    if (r < hi) {
      const float e = expf(scores[(size_t)r * 4 + h] - m);
      ssum += e;
      w0 += e * v[3 * (size_t)r + 0];
      w1 += e * v[3 * (size_t)r + 1];
      w2 += e * v[3 * (size_t)r + 2];
    }
  }
  #pragma unroll
  for (int o = 4; o < 64; o <<= 1) {
    ssum += __shfl_xor(ssum, o);
    w0   += __shfl_xor(w0, o);
    w1   += __shfl_xor(w1, o);
    w2   += __shfl_xor(w2, o);
  }

  if (ro == 0) {
    const float inv = (hi > lo) ? (1.f / ssum) : 0.f;
    out[(size_t)seg * 12 + h * 3 + 0] = w0 * inv;
    out[(size_t)seg * 12 + h * 3 + 1] = w1 * inv;
    out[(size_t)seg * 12 + h * 3 + 2] = w2 * inv;
  }
}

// ---------------------------------------------------------------------------
extern "C" void kernel_launch(void* const* d_in, const int* in_sizes, int n_in,
                              void* d_out, int out_size, void* d_ws, size_t ws_size,
                              hipStream_t stream)
{
  const float* v     = (const float*)d_in[0];
  const float* af    = (const float*)d_in[1];
  const int*   gidx  = (const int*)  d_in[2];
  const float* fw    = (const float*)d_in[4];
  const float* fb    = (const float*)d_in[5];
  const float* ln1g  = (const float*)d_in[6];
  const float* ln1b  = (const float*)d_in[7];
  const float* wsw1  = (const float*)d_in[8];
  const float* wss1  = (const float*)d_in[9];
  const float* wsig1 = (const float*)d_in[10];
  const float* bsig1 = (const float*)d_in[11];
  const float* wsc1  = (const float*)d_in[12];
  const float* ln2g  = (const float*)d_in[13];
  const float* ln2b  = (const float*)d_in[14];
  const float* wsw2  = (const float*)d_in[15];
  const float* wss2  = (const float*)d_in[16];
  const float* wsig2 = (const float*)d_in[17];
  const float* bsig2 = (const float*)d_in[18];
  const float* wsc2  = (const float*)d_in[19];
  const float* outw  = (const float*)d_in[20];
  const float* outb  = (const float*)d_in[21];

  const int N = in_sizes[0] / 3;
  const int E = out_size / 12;

  float* scores = (float*)d_ws;                                   // N*4 f32 = 16 MB
  unsigned short* wcv = (unsigned short*)((char*)d_ws + (size_t)N * 4 * sizeof(float));

  hipLaunchKernelGGL(iab_wconv_kernel, dim3((NGRP_ALL + 255) / 256), dim3(256), 0, stream,
                     wsw1, wss1, wsig1, wsc1, wsw2, wss2, wsig2, wsc2, outw, wcv);

  hipLaunchKernelGGL(iab_rows_mfma, dim3((N + ROWS - 1) / ROWS), dim3(THREADS), 0, stream,
                     v, af, fw, fb, ln1g, ln1b, bsig1, ln2g, ln2b, bsig2, outb,
                     wcv, scores, N);

  hipLaunchKernelGGL(iab_segpool_kernel, dim3((E + 3) / 4), dim3(256), 0, stream,
                     scores, v, gidx, (float*)d_out, N, E);
}

// Round 6
// 1947.784 us; speedup vs baseline: 3.0748x; 1.0563x over previous
//
#include <hip/hip_runtime.h>
#include <math.h>

#define DIN   192
#define HD    256
#define ROWS  64
#define THREADS 512
#define LSTR  256

typedef __bf16 bf16_t;
typedef bf16_t bf16x8 __attribute__((ext_vector_type(8)));
typedef float  f32x16 __attribute__((ext_vector_type(16)));

static __device__ __forceinline__ f32x16 mfma32(bf16x8 a, bf16x8 b, f32x16 c) {
  return __builtin_amdgcn_mfma_f32_32x32x16_bf16(a, b, c, 0, 0, 0);
}
static __device__ __forceinline__ unsigned short f2bfu(float f) {
  bf16_t h = (bf16_t)f; unsigned short u; __builtin_memcpy(&u, &h, 2); return u;
}
static __device__ __forceinline__ float bfu2f(unsigned short u) {
  unsigned x = ((unsigned)u) << 16; float f; __builtin_memcpy(&f, &x, 4); return f;
}
static __device__ __forceinline__ unsigned pk2(float a, float b) {
  return (unsigned)f2bfu(a) | ((unsigned)f2bfu(b) << 16);
}
static __device__ __forceinline__ float lo16(unsigned u) { return bfu2f((unsigned short)(u & 0xffff)); }
static __device__ __forceinline__ float hi16(unsigned u) { return bfu2f((unsigned short)(u >> 16)); }
static __device__ __forceinline__ float sigm(float x) {
  return __builtin_amdgcn_rcpf(1.f + __expf(-x));
}
// XOR-swizzled LDS element index
static __device__ __forceinline__ int lidx(int row, int col) {
  return row * LSTR + (col ^ ((row & 7) << 3));
}
// C-layout row for 32x32 MFMA (m74/m101): row = (r&3) + 8*(r>>2) + 4*kg
static __device__ __forceinline__ int crow(int r, int kg) {
  return (r & 3) + 8 * (r >> 2) + 4 * kg;
}

// bf16 weight regions (elements) inside d_ws after the scores buffer.
// Big matrices in MFMA-B-fragment order: ((tile*KS + ks)*64 + lane)*8 + j
// where tile=ocol>>5, lane=kg*32+(ocol&31), k = ks*16 + kg*8 + j.
// out_w stored as ONE fragment tile padded 4 -> 32 cols (zeros).
#define OFF_WSW1 0
#define OFF_WSS1 49152
#define OFF_WSG1 98304
#define OFF_WSC1 147456
#define OFF_WSW2 212992
#define OFF_WSS2 278528
#define OFF_WSG2 344064
#define OFF_WSC2 409600
#define OFF_WOUT 475136     // 16 ks * 64 lanes * 8 = 8192 elems (padded frag)
#define NGRP_REORD 59392    // 3*6144 + 5*8192 groups of 8
#define NGRP_ALL   60416    // + 1024 groups for padded out_w fragment

__global__ void iab_wconv_kernel(const float* __restrict__ a0, const float* __restrict__ a1,
                                 const float* __restrict__ a2, const float* __restrict__ a3,
                                 const float* __restrict__ a4, const float* __restrict__ a5,
                                 const float* __restrict__ a6, const float* __restrict__ a7,
                                 const float* __restrict__ a8, unsigned short* __restrict__ out)
{
  const int i = blockIdx.x * 256 + threadIdx.x;
  if (i >= NGRP_ALL) return;
  if (i >= NGRP_REORD) {                       // out_w padded fragment tile
    const int g  = i - NGRP_REORD;             // [0, 1024)
    const int ks = g >> 6;
    const int ln = g & 63;
    const int col = ln & 31;
    const int kg  = ln >> 5;
    #pragma unroll
    for (int j = 0; j < 8; ++j) {
      const float vv = (col < 4) ? a8[col * 256 + ks * 16 + kg * 8 + j] : 0.f;
      out[OFF_WOUT + (size_t)g * 8 + j] = f2bfu(vv);
    }
    return;
  }
  const float* src; int off, Kd, g;
  if      (i < 6144)  { src = a0; off = OFF_WSW1; Kd = 192; g = i; }
  else if (i < 12288) { src = a1; off = OFF_WSS1; Kd = 192; g = i - 6144; }
  else if (i < 18432) { src = a2; off = OFF_WSG1; Kd = 192; g = i - 12288; }
  else if (i < 26624) { src = a3; off = OFF_WSC1; Kd = 256; g = i - 18432; }
  else if (i < 34816) { src = a4; off = OFF_WSW2; Kd = 256; g = i - 26624; }
  else if (i < 43008) { src = a5; off = OFF_WSS2; Kd = 256; g = i - 34816; }
  else if (i < 51200) { src = a6; off = OFF_WSG2; Kd = 256; g = i - 43008; }
  else                { src = a7; off = OFF_WSC2; Kd = 256; g = i - 51200; }
  const int KS   = Kd >> 4;
  const int tile = g / (KS * 64);
  const int rem  = g - tile * (KS * 64);
  const int ks   = rem >> 6;
  const int ln   = rem & 63;
  const float* sp = src + (size_t)(tile * 32 + (ln & 31)) * Kd + ks * 16 + (ln >> 5) * 8;
  #pragma unroll
  for (int j = 0; j < 8; ++j) out[off + (size_t)g * 8 + j] = f2bfu(sp[j]);
}

// single-matrix GEMM pass, both 32-row m-tiles
template<int KS>
static __device__ __forceinline__ void gemm2(const unsigned short* __restrict__ Wt,
                                             const unsigned short* __restrict__ sIn,
                                             int l31, int kg, int xr,
                                             f32x16& acc0, f32x16& acc1)
{
  #pragma unroll 4
  for (int ks = 0; ks < KS; ++ks) {
    const bf16x8 Wc = *(const bf16x8*)(Wt + ks * 512);
    const int col = (ks * 16 + kg * 8) ^ xr;
    const bf16x8 A0 = *(const bf16x8*)(sIn + l31 * LSTR + col);
    const bf16x8 A1 = *(const bf16x8*)(sIn + (l31 + 32) * LSTR + col);
    acc0 = mfma32(A0, Wc, acc0);
    acc1 = mfma32(A1, Wc, acc1);
  }
}

// paired GEMM pass: two weight matrices sharing the same A operand stream
template<int KS>
static __device__ __forceinline__ void gemm2p(const unsigned short* __restrict__ Wa,
                                              const unsigned short* __restrict__ Wb,
                                              const unsigned short* __restrict__ sIn,
                                              int l31, int kg, int xr,
                                              f32x16& u0, f32x16& u1,
                                              f32x16& s0, f32x16& s1)
{
  #pragma unroll 2
  for (int ks = 0; ks < KS; ++ks) {
    const bf16x8 wa = *(const bf16x8*)(Wa + ks * 512);
    const bf16x8 wb = *(const bf16x8*)(Wb + ks * 512);
    const int col = (ks * 16 + kg * 8) ^ xr;
    const bf16x8 A0 = *(const bf16x8*)(sIn + l31 * LSTR + col);
    const bf16x8 A1 = *(const bf16x8*)(sIn + (l31 + 32) * LSTR + col);
    u0 = mfma32(A0, wa, u0);
    s0 = mfma32(A0, wb, s0);
    u1 = mfma32(A1, wa, u1);
    s1 = mfma32(A1, wb, s1);
  }
}

// b = silu(u) * s -> bf16 LDS (one m-tile), straight from f32 accumulators
static __device__ __forceinline__ void storeSilu2(unsigned short* dst, const f32x16 u,
                                                  const f32x16 s, int mt, int kg, int ocol)
{
  #pragma unroll
  for (int i = 0; i < 16; ++i) {
    const float x = u[i];
    dst[lidx(mt * 32 + crow(i, kg), ocol)] = f2bfu(x * sigm(x) * s[i]);
  }
}

// write 16 packed words (2 m-tiles) to LDS
static __device__ __forceinline__ void storePk(unsigned short* dst, const unsigned* xp,
                                               int kg, int ocol)
{
  #pragma unroll
  for (int mt = 0; mt < 2; ++mt) {
    #pragma unroll
    for (int p = 0; p < 8; ++p) {
      const int r0 = 2 * p;
      const int row0 = mt * 32 + crow(r0, kg);
      const unsigned pk = xp[mt * 8 + p];
      dst[lidx(row0,     ocol)] = (unsigned short)(pk & 0xffff);
      dst[lidx(row0 + 1, ocol)] = (unsigned short)(pk >> 16);
    }
  }
}

// ---------------------------------------------------------------------------
// Main fused kernel. 64 rows/block, 512 threads (8 waves).
// Wave w owns ocols [32w, 32w+32); 2 m-tiles of 32 rows. 32x32x16 MFMA.
// sw/ss GEMMs paired (shared A reads); scores via MFMA with padded out_w.
// ---------------------------------------------------------------------------
__global__ __launch_bounds__(THREADS, 2)
void iab_rows_mfma(
    const float* __restrict__ v, const float* __restrict__ af,
    const float* __restrict__ fw, const float* __restrict__ fb,
    const float* __restrict__ ln1g, const float* __restrict__ ln1b,
    const float* __restrict__ bsig1,
    const float* __restrict__ ln2g, const float* __restrict__ ln2b,
    const float* __restrict__ bsig2,
    const float* __restrict__ outb,
    const unsigned short* __restrict__ wc,
    float* __restrict__ scores, int N)
{
  __shared__ __align__(16) unsigned short sA[ROWS * LSTR];  // xhat1 -> x2 -> xhat2 -> xf
  __shared__ __align__(16) unsigned short sB[ROWS * LSTR];  // b1 -> b2

  const int t    = threadIdx.x;
  const int w    = t >> 6;
  const int lane = t & 63;
  const int l31  = lane & 31;
  const int kg   = lane >> 5;
  const int xr   = (lane & 7) << 3;     // row&7 == lane&7 for both m-tiles
  const int ocol = w * 32 + l31;
  const int row0 = blockIdx.x * ROWS;

  const unsigned short* WtSW1 = wc + OFF_WSW1 + (w * 12 * 64 + lane) * 8;
  const unsigned short* WtSS1 = wc + OFF_WSS1 + (w * 12 * 64 + lane) * 8;
  const unsigned short* WtSG1 = wc + OFF_WSG1 + (w * 12 * 64 + lane) * 8;
  const unsigned short* WtSC1 = wc + OFF_WSC1 + (w * 16 * 64 + lane) * 8;
  const unsigned short* WtSW2 = wc + OFF_WSW2 + (w * 16 * 64 + lane) * 8;
  const unsigned short* WtSS2 = wc + OFF_WSS2 + (w * 16 * 64 + lane) * 8;
  const unsigned short* WtSG2 = wc + OFF_WSG2 + (w * 16 * 64 + lane) * 8;
  const unsigned short* WtSC2 = wc + OFF_WSC2 + (w * 16 * 64 + lane) * 8;

  // ---- P0: fourier features + concat + LN1 -> sA ----
  {
    const float fwl = fw[lane], fbl = fb[lane];
    const float g1a = ln1g[lane], g1b = ln1g[lane + 64], g1c = ln1g[lane + 128];
    const float o1a = ln1b[lane], o1b = ln1b[lane + 64], o1c = ln1b[lane + 128];
    for (int rr = 0; rr < 8; ++rr) {
      const int r = w * 8 + rr;
      const int g = row0 + r;
      float e0 = 0.f, e1 = 0.f, e2 = 0.f;
      if (g < N) {
        const float vx = v[3 * (size_t)g + 0];
        const float vy = v[3 * (size_t)g + 1];
        const float vz = v[3 * (size_t)g + 2];
        const float nrm = sqrtf(vx * vx + vy * vy + vz * vz);
        e0 = __cosf(6.283185307179586f * (nrm * fwl + fbl));
        const float* a = af + (size_t)g * 128;
        e1 = a[lane];
        e2 = a[lane + 64];
      }
      float s  = e0 + e1 + e2;
      float sq = e0 * e0 + e1 * e1 + e2 * e2;
      #pragma unroll
      for (int o = 32; o >= 1; o >>= 1) {
        s  += __shfl_xor(s,  o);
        sq += __shfl_xor(sq, o);
      }
      const float mean = s * (1.f / 192.f);
      const float var  = fmaxf(sq * (1.f / 192.f) - mean * mean, 0.f);
      const float rstd = rsqrtf(var + 1e-5f);
      sA[lidx(r, lane)]       = f2bfu((e0 - mean) * rstd * g1a + o1a);
      sA[lidx(r, lane + 64)]  = f2bfu((e1 - mean) * rstd * g1b + o1b);
      sA[lidx(r, lane + 128)] = f2bfu((e2 - mean) * rstd * g1c + o1c);
    }
  }
  __syncthreads();

  unsigned x2p[16];   // packed x2 (TB1 out), carried for TB2 residual

  // ---- B1: u,s = xhat1 @ {Wsw1,Wss1}^T (paired); b1 = silu(u)*s -> sB ----
  {
    f32x16 u0{}, u1{}, s0{}, s1{};
    gemm2p<12>(WtSW1, WtSS1, sA, l31, kg, xr, u0, u1, s0, s1);
    storeSilu2(sB, u0, s0, 0, kg, ocol);
    storeSilu2(sB, u1, s1, 1, kg, ocol);
  }

  // ---- C-sg: sig = sigmoid(xhat1 @ Wsg1^T + b)  (reads sA only; pre-barrier) ----
  unsigned sgp[16];
  {
    f32x16 g0{}, g1{};
    gemm2<12>(WtSG1, sA, l31, kg, xr, g0, g1);
    const float bias = bsig1[ocol];
    #pragma unroll
    for (int p = 0; p < 8; ++p) {
      sgp[p]     = pk2(sigm(g0[2*p] + bias), sigm(g0[2*p+1] + bias));
      sgp[8 + p] = pk2(sigm(g1[2*p] + bias), sigm(g1[2*p+1] + bias));
    }
  }
  __syncthreads();   // b1 visible; all sA (xhat1) reads complete

  // ---- C-sc: c = b1 @ Wsc1^T; x2 = sig * c -> regs + sA ----
  {
    f32x16 c0{}, c1{};
    gemm2<16>(WtSC1, sB, l31, kg, xr, c0, c1);
    #pragma unroll
    for (int p = 0; p < 8; ++p) {
      x2p[p]     = pk2(lo16(sgp[p])   * c0[2*p], hi16(sgp[p])   * c0[2*p+1]);
      x2p[8 + p] = pk2(lo16(sgp[8+p]) * c1[2*p], hi16(sgp[8+p]) * c1[2*p+1]);
    }
    storePk(sA, x2p, kg, ocol);   // x2 -> sA (xhat1 dead)
  }
  __syncthreads();

  // ---- LN2: in-place on sA ----
  {
    float g2v[4], o2v[4];
    #pragma unroll
    for (int i = 0; i < 4; ++i) { g2v[i] = ln2g[lane + 64 * i]; o2v[i] = ln2b[lane + 64 * i]; }
    for (int rr = 0; rr < 8; ++rr) {
      const int r = w * 8 + rr;
      float e[4];
      #pragma unroll
      for (int i = 0; i < 4; ++i) e[i] = bfu2f(sA[lidx(r, lane + 64 * i)]);
      float s  = e[0] + e[1] + e[2] + e[3];
      float sq = e[0]*e[0] + e[1]*e[1] + e[2]*e[2] + e[3]*e[3];
      #pragma unroll
      for (int o = 32; o >= 1; o >>= 1) {
        s  += __shfl_xor(s,  o);
        sq += __shfl_xor(sq, o);
      }
      const float mean = s * (1.f / 256.f);
      const float var  = fmaxf(sq * (1.f / 256.f) - mean * mean, 0.f);
      const float rstd = rsqrtf(var + 1e-5f);
      #pragma unroll
      for (int i = 0; i < 4; ++i)
        sA[lidx(r, lane + 64 * i)] = f2bfu((e[i] - mean) * rstd * g2v[i] + o2v[i]);
    }
  }
  __syncthreads();

  // ---- D1: u2,s2 = xhat2 @ {Wsw2,Wss2}^T (paired); b2 = silu(u2)*s2 -> sB ----
  {
    f32x16 u0{}, u1{}, s0{}, s1{};
    gemm2p<16>(WtSW2, WtSS2, sA, l31, kg, xr, u0, u1, s0, s1);
    storeSilu2(sB, u0, s0, 0, kg, ocol);
    storeSilu2(sB, u1, s1, 1, kg, ocol);
  }

  // ---- D23-sg: sig2 = sigmoid(xhat2 @ Wsg2^T + b)  (pre-barrier) ----
  {
    f32x16 g0{}, g1{};
    gemm2<16>(WtSG2, sA, l31, kg, xr, g0, g1);
    const float bias = bsig2[ocol];
    #pragma unroll
    for (int p = 0; p < 8; ++p) {
      sgp[p]     = pk2(sigm(g0[2*p] + bias), sigm(g0[2*p+1] + bias));
      sgp[8 + p] = pk2(sigm(g1[2*p] + bias), sigm(g1[2*p+1] + bias));
    }
  }
  __syncthreads();   // b2 visible; all sA (xhat2) reads complete

  // ---- D23-sc: c2 = b2 @ Wsc2^T; xf = x2 + sig2*c2 -> sA ----
  {
    f32x16 c0{}, c1{};
    gemm2<16>(WtSC2, sB, l31, kg, xr, c0, c1);
    #pragma unroll
    for (int p = 0; p < 8; ++p) {
      x2p[p]     = pk2(lo16(x2p[p])   + lo16(sgp[p])   * c0[2*p],
                       hi16(x2p[p])   + hi16(sgp[p])   * c0[2*p+1]);
      x2p[8 + p] = pk2(lo16(x2p[8+p]) + lo16(sgp[8+p]) * c1[2*p],
                       hi16(x2p[8+p]) + hi16(sgp[8+p]) * c1[2*p+1]);
    }
    storePk(sA, x2p, kg, ocol);
  }
  __syncthreads();

  // ---- F: scores = xf @ out_w^T + out_b via MFMA (waves 0-1 only) ----
  if (w < 2) {
    const unsigned short* WtF = wc + OFF_WOUT + (size_t)lane * 8;
    f32x16 c{};
    #pragma unroll 4
    for (int ks = 0; ks < 16; ++ks) {
      const bf16x8 wf = *(const bf16x8*)(WtF + ks * 512);
      const int col = (ks * 16 + kg * 8) ^ xr;
      const bf16x8 A = *(const bf16x8*)(sA + (w * 32 + l31) * LSTR + col);
      c = mfma32(A, wf, c);
    }
    if (l31 < 4) {
      const float bias = outb[l31];
      #pragma unroll
      for (int i = 0; i < 16; ++i) {
        const int g = row0 + w * 32 + crow(i, kg);
        if (g < N) scores[(size_t)g * 4 + l31] = c[i] + bias;
      }
    }
  }
}

// ---------------------------------------------------------------------------
// Segment softmax + weighted 3-vector pooling (sorted indices, wave/segment).
// ---------------------------------------------------------------------------
__device__ __forceinline__ int iab_lower_bound(const int* __restrict__ a, int n, int key)
{
  int lo = 0, hi = n;
  while (lo < hi) {
    const int mid = (lo + hi) >> 1;
    if (a[mid] < key) lo = mid + 1; else hi = mid;
  }
  return lo;
}

__global__ __launch_bounds__(256)
void iab_segpool_kernel(const float* __restrict__ scores,
                        const float* __restrict__ v,
                        const int* __restrict__ gidx,
                        float* __restrict__ out, int N, int E)
{
  const int seg  = blockIdx.x * 4 + (threadIdx.x >> 6);
  const int lane = threadIdx.x & 63;
  if (seg >= E) return;

  const int lo = iab_lower_bound(gidx, N, seg);
  const int hi = iab_lower_bound(gidx, N, seg + 1);

  const int h  = lane & 3;
  const int ro = lane >> 2;

  float m = -INFINITY;
  for (int base = lo; base < hi; base += 16) {
    const int r = base + ro;
    if (r < hi) m = fmaxf(m, scores[(size_t)r * 4 + h]);
  }
  #pragma unroll
  for (int o = 4; o < 64; o <<= 1) m = fmaxf(m, __shfl_xor(m, o));

  float ssum = 0.f, w0 = 0.f, w1 = 0.f, w2 = 0.f;
  for (int base = lo; base < hi; base += 16) {
    const int r = base + ro;
    if (r < hi) {
      const float e = expf(scores[(size_t)r * 4 + h] - m);
      ssum += e;
      w0 += e * v[3 * (size_t)r + 0];
      w1 += e * v[3 * (size_t)r + 1];
      w2 += e * v[3 * (size_t)r + 2];
    }
  }
  #pragma unroll
  for (int o = 4; o < 64; o <<= 1) {
    ssum += __shfl_xor(ssum, o);
    w0   += __shfl_xor(w0, o);
    w1   += __shfl_xor(w1, o);
    w2   += __shfl_xor(w2, o);
  }

  if (ro == 0) {
    const float inv = (hi > lo) ? (1.f / ssum) : 0.f;
    out[(size_t)seg * 12 + h * 3 + 0] = w0 * inv;
    out[(size_t)seg * 12 + h * 3 + 1] = w1 * inv;
    out[(size_t)seg * 12 + h * 3 + 2] = w2 * inv;
  }
}

// ---------------------------------------------------------------------------
extern "C" void kernel_launch(void* const* d_in, const int* in_sizes, int n_in,
                              void* d_out, int out_size, void* d_ws, size_t ws_size,
                              hipStream_t stream)
{
  const float* v     = (const float*)d_in[0];
  const float* af    = (const float*)d_in[1];
  const int*   gidx  = (const int*)  d_in[2];
  const float* fw    = (const float*)d_in[4];
  const float* fb    = (const float*)d_in[5];
  const float* ln1g  = (const float*)d_in[6];
  const float* ln1b  = (const float*)d_in[7];
  const float* wsw1  = (const float*)d_in[8];
  const float* wss1  = (const float*)d_in[9];
  const float* wsig1 = (const float*)d_in[10];
  const float* bsig1 = (const float*)d_in[11];
  const float* wsc1  = (const float*)d_in[12];
  const float* ln2g  = (const float*)d_in[13];
  const float* ln2b  = (const float*)d_in[14];
  const float* wsw2  = (const float*)d_in[15];
  const float* wss2  = (const float*)d_in[16];
  const float* wsig2 = (const float*)d_in[17];
  const float* bsig2 = (const float*)d_in[18];
  const float* wsc2  = (const float*)d_in[19];
  const float* outw  = (const float*)d_in[20];
  const float* outb  = (const float*)d_in[21];

  const int N = in_sizes[0] / 3;
  const int E = out_size / 12;

  float* scores = (float*)d_ws;                                   // N*4 f32 = 16 MB
  unsigned short* wcv = (unsigned short*)((char*)d_ws + (size_t)N * 4 * sizeof(float));

  hipLaunchKernelGGL(iab_wconv_kernel, dim3((NGRP_ALL + 255) / 256), dim3(256), 0, stream,
                     wsw1, wss1, wsig1, wsc1, wsw2, wss2, wsig2, wsc2, outw, wcv);

  hipLaunchKernelGGL(iab_rows_mfma, dim3((N + ROWS - 1) / ROWS), dim3(THREADS), 0, stream,
                     v, af, fw, fb, ln1g, ln1b, bsig1, ln2g, ln2b, bsig2, outb,
                     wcv, scores, N);

  hipLaunchKernelGGL(iab_segpool_kernel, dim3((E + 3) / 4), dim3(256), 0, stream,
                     scores, v, gidx, (float*)d_out, N, E);
}